// Round 8
// baseline (390.616 us; speedup 1.0000x reference)
//
#include <hip/hip_runtime.h>
#include <hip/hip_bf16.h>

// ---------------------------------------------------------------------------
// MHA forward: fp32 I/O, bf16 MFMA compute. B=4,S=2048,D=1024,H=16,DK=64.
// 4 dispatches:
//   0. cvt Wo -> bf16 (4 MB, ~3 µs; Wo reused 8192x by gemm_o)
//   1. proj_kernel grid(8,64,3): z=0 Qh=(Q@Wq^T+bq)*qscale, z=1 Kh, z=2
//      Vt=(V@Wv^T+bv)^T. fp32->bf16 conversion fused into staging.
//      DEPTH-2 register prefetch: staged loads get 2 compute phases (~650cy)
//      of flight to cover cold-HBM latency (~600-900cy); depth-1 only gave
//      ~300cy (R6/R7: all pipes idle, MfmaUtil 13%).
//   2. attn_kernel: flash attention (sum-only softmax; swapped QK^T,
//      in-register P, T14 async-stage, 32 q-rows/wave).
//   3. gemm_o: out = ctx@Wo^T+bo. gl_lds + LDS double-buffer + counted
//      vmcnt(4) (R5-proven structure).
// ---------------------------------------------------------------------------

typedef float  f32x4  __attribute__((ext_vector_type(4)));
typedef __bf16 bf16x8 __attribute__((ext_vector_type(8)));
typedef short  s16x8  __attribute__((ext_vector_type(8)));
typedef int    i32x4  __attribute__((ext_vector_type(4)));

#define MFMA16(a,b,c) __builtin_amdgcn_mfma_f32_16x16x32_bf16((a),(b),(c),0,0,0)

__device__ __forceinline__ unsigned short f2bf(float f) {
    union { float f; unsigned u; } v; v.f = f;
    unsigned r = v.u + 0x7fffu + ((v.u >> 16) & 1u);   // RNE
    return (unsigned short)(r >> 16);
}

__device__ __forceinline__ s16x8 cvt8(const float* __restrict__ p) {
    f32x4 x = *(const f32x4*)p;
    f32x4 y = *(const f32x4*)(p + 4);
    s16x8 r;
    r[0] = (short)f2bf(x[0]); r[1] = (short)f2bf(x[1]);
    r[2] = (short)f2bf(x[2]); r[3] = (short)f2bf(x[3]);
    r[4] = (short)f2bf(y[0]); r[5] = (short)f2bf(y[1]);
    r[6] = (short)f2bf(y[2]); r[7] = (short)f2bf(y[3]);
    return r;
}

// async global->LDS, 16 B per lane; LDS dest = wave-uniform base + lane*16
__device__ __forceinline__ void gl_lds16(const void* g, void* l) {
    __builtin_amdgcn_global_load_lds(
        (const __attribute__((address_space(1))) unsigned int*)g,
        (__attribute__((address_space(3))) unsigned int*)l, 16, 0, 0);
}

// raw v_exp_f32: D = 2^S0
__device__ __forceinline__ float exp2_fast(float x) {
    float r;
    asm("v_exp_f32 %0, %1" : "=v"(r) : "v"(x));
    return r;
}

// pack 2 f32 -> 1 dword of 2 bf16 (RNE). D[15:0]=bf16(lo), D[31:16]=bf16(hi)
__device__ __forceinline__ int cvtpk_bf16(float lo, float hi) {
    int r;
    asm("v_cvt_pk_bf16_f32 %0, %1, %2" : "=v"(r) : "v"(lo), "v"(hi));
    return r;
}
// 8 fp32 (two f32x4) -> 8 bf16 shorts, RNE (4 cvt_pk ops)
__device__ __forceinline__ s16x8 pk8(f32x4 x, f32x4 y) {
    i32x4 r;
    r[0] = cvtpk_bf16(x[0], x[1]);
    r[1] = cvtpk_bf16(x[2], x[3]);
    r[2] = cvtpk_bf16(y[0], y[1]);
    r[3] = cvtpk_bf16(y[2], y[3]);
    return __builtin_bit_cast(s16x8, r);
}
// a.row1(32 lanes) <-> b.row0: a'=[a.lo32,b.lo32], b'=[a.hi32,b.hi32]
__device__ __forceinline__ void plswap32(int& a, int& b) {
    asm("v_permlane32_swap_b32 %0, %1" : "+v"(a), "+v"(b));
}
// odd 16-rows of a <-> even 16-rows of b
__device__ __forceinline__ void plswap16(int& a, int& b) {
    asm("v_permlane16_swap_b32 %0, %1" : "+v"(a), "+v"(b));
}

// P-row (lane-local, S^T layout) -> two PV A-fragment dwords x2
__device__ __forceinline__ void pack_pf(const f32x4 pe[4], bf16x8& pf0, bf16x8& pf1) {
    int a0 = cvtpk_bf16(pe[0][0], pe[0][1]);
    int a1 = cvtpk_bf16(pe[0][2], pe[0][3]);
    int b0 = cvtpk_bf16(pe[1][0], pe[1][1]);
    int b1 = cvtpk_bf16(pe[1][2], pe[1][3]);
    plswap32(a0, b0); plswap32(a1, b1);
    plswap16(a0, b0); plswap16(a1, b1);
    i32x4 f0; f0[0] = a0; f0[1] = a1; f0[2] = b0; f0[3] = b1;
    int c0 = cvtpk_bf16(pe[2][0], pe[2][1]);
    int c1 = cvtpk_bf16(pe[2][2], pe[2][3]);
    int d0 = cvtpk_bf16(pe[3][0], pe[3][1]);
    int d1 = cvtpk_bf16(pe[3][2], pe[3][3]);
    plswap32(c0, d0); plswap32(c1, d1);
    plswap16(c0, d0); plswap16(c1, d1);
    i32x4 f1; f1[0] = c0; f1[1] = c1; f1[2] = d0; f1[3] = d1;
    pf0 = __builtin_bit_cast(bf16x8, f0);
    pf1 = __builtin_bit_cast(bf16x8, f1);
}

// ---------------------------------------------------------------------------
__global__ __launch_bounds__(256) void cvt_kernel(
    const float* __restrict__ src, unsigned short* __restrict__ dst, int n8)
{
    int i = blockIdx.x * 256 + threadIdx.x;
    if (i < n8) *(s16x8*)(dst + (size_t)i * 8) = cvt8(src + (size_t)i * 8);
}

// ---------------------------------------------------------------------------
// Fused QKV projection. Grid (8,64,3), 256 threads, 128x128 tile, BK=32.
// z=0: Qh[b,h,s,d] = (Q@Wq^T+bq)*qscale  (bf16, head-split)
// z=1: Kh likewise, scale 1
// z=2: Vt[b,h,d,s] = (V@Wv^T+bv)^T       (A-side=Wv, W-side=V)
// fp32 inputs converted to bf16 via cvt_pk during ds_write.
// DEPTH-2 prefetch: two named reg sets rA/rB (static indexing only), loop
// unrolled over 2 BK=32 sub-tiles; set X written to LDS then immediately
// reloaded from k+64 -> in flight across TWO compute phases (~650 cy),
// covering cold-HBM latency. __syncthreads does not drain reg-dest global
// loads, so the prefetch survives the barriers.
// XCD decode: blockIdx.x (=XCD id) selects the operand chunk shared by that
// XCD's 8 y-blocks -> panel stays L2-resident.
// ---------------------------------------------------------------------------
__global__ __launch_bounds__(256) void proj_kernel(
    const float* __restrict__ Qf, const float* __restrict__ Kf,
    const float* __restrict__ Vf,
    const float* __restrict__ Wqf, const float* __restrict__ Wkf,
    const float* __restrict__ Wvf,
    const float* __restrict__ bqf, const float* __restrict__ bkf,
    const float* __restrict__ bvf,
    unsigned short* __restrict__ Qh, unsigned short* __restrict__ Kh,
    unsigned short* __restrict__ Vtw, float qscale)
{
    constexpr int K = 1024;
    __shared__ unsigned short Ash[128 * 32];
    __shared__ unsigned short Bsh[128 * 32];

    const int t    = threadIdx.x;
    const int w    = t >> 6;
    const int lane = t & 63;
    const int wm   = w >> 1, wn = w & 1;
    const int lr   = lane & 15, quad = lane >> 4;

    const int z = blockIdx.z;
    const float *Af, *Wf, *bias;
    float scale;
    unsigned short* out;
    if (z == 0)      { Af = Qf;  Wf = Wqf; bias = bqf; out = Qh;  scale = qscale; }
    else if (z == 1) { Af = Kf;  Wf = Wkf; bias = bkf; out = Kh;  scale = 1.0f; }
    else             { Af = Wvf; Wf = Vf;  bias = bvf; out = Vtw; scale = 1.0f; }

    int m0, n0;
    if (z < 2) {   // m: 64 tiles (seq), n: 8 tiles (weight). XCD x owns m-chunk.
        m0 = (blockIdx.x * 8 + (blockIdx.y >> 3)) * 128;
        n0 = (blockIdx.y & 7) * 128;
    } else {       // m: 8 tiles (Wv rows), n: 64 tiles (V rows). XCD x owns V-chunk.
        m0 = (blockIdx.y & 7) * 128;
        n0 = (blockIdx.x * 8 + (blockIdx.y >> 3)) * 128;
    }

    // staging: thread t handles LDS row srow (64-row half), shorts [skp,skp+8)
    const int srow = t >> 2;
    const int skp  = (t & 3) * 8;

    const float* Ap0 = Af + (size_t)(m0 + srow) * K + skp;
    const float* Ap1 = Ap0 + (size_t)64 * K;
    const float* Wp0 = Wf + (size_t)(n0 + srow) * K + skp;
    const float* Wp1 = Wp0 + (size_t)64 * K;
    unsigned short* dA = &Ash[srow * 32 + skp];
    unsigned short* dB = &Bsh[srow * 32 + skp];

    f32x4 rA[8], rB[8];   // two staging sets; constant indices only (rule #20)
#define LOADSET(R, kk) do {                                                   \
        R[0] = *(const f32x4*)(Ap0 + (kk)); R[1] = *(const f32x4*)(Ap0 + (kk) + 4); \
        R[2] = *(const f32x4*)(Ap1 + (kk)); R[3] = *(const f32x4*)(Ap1 + (kk) + 4); \
        R[4] = *(const f32x4*)(Wp0 + (kk)); R[5] = *(const f32x4*)(Wp0 + (kk) + 4); \
        R[6] = *(const f32x4*)(Wp1 + (kk)); R[7] = *(const f32x4*)(Wp1 + (kk) + 4); \
    } while (0)
#define WRITESET(R) do {                          \
        *(s16x8*)dA             = pk8(R[0], R[1]); \
        *(s16x8*)(dA + 64 * 32) = pk8(R[2], R[3]); \
        *(s16x8*)dB             = pk8(R[4], R[5]); \
        *(s16x8*)(dB + 64 * 32) = pk8(R[6], R[7]); \
    } while (0)
#define PCOMPUTE do {                                                         \
        bf16x8 af[4], bw[4];                                                  \
        _Pragma("unroll")                                                     \
        for (int i = 0; i < 4; i++)                                           \
            af[i] = *(const bf16x8*)&Ash[(wm * 64 + i * 16 + lr) * 32 + quad * 8]; \
        _Pragma("unroll")                                                     \
        for (int j = 0; j < 4; j++)                                           \
            bw[j] = *(const bf16x8*)&Bsh[(wn * 64 + j * 16 + lr) * 32 + quad * 8]; \
        _Pragma("unroll")                                                     \
        for (int i = 0; i < 4; i++)                                           \
            _Pragma("unroll")                                                 \
            for (int j = 0; j < 4; j++)                                       \
                acc[i][j] = MFMA16(af[i], bw[j], acc[i][j]);                  \
    } while (0)

    f32x4 acc[4][4] = {};
    LOADSET(rA, 0);      // prologue: tiles 0 and 32 in flight
    LOADSET(rB, 32);

    for (int k0 = 0; k0 < K; k0 += 64) {
        // ---- sub-iter 0: tile k0 (set A); prefetch k0+64
        __syncthreads();                 // prior tile's LDS reads complete
        WRITESET(rA);
        LOADSET(rA, (k0 + 64) & 1023);   // wraps on last iter (harmless)
        __syncthreads();                 // staged tile visible
        PCOMPUTE;
        // ---- sub-iter 1: tile k0+32 (set B); prefetch k0+96
        __syncthreads();
        WRITESET(rB);
        LOADSET(rB, (k0 + 96) & 1023);
        __syncthreads();
        PCOMPUTE;
    }
#undef LOADSET
#undef WRITESET
#undef PCOMPUTE

    // epilogue: C/D row = quad*4+r (m-side), col = lr (n-side)
#pragma unroll
    for (int i = 0; i < 4; i++) {
#pragma unroll
        for (int j = 0; j < 4; j++) {
            const int n = n0 + wn * 64 + j * 16 + lr;
#pragma unroll
            for (int r = 0; r < 4; r++) {
                const int m = m0 + wm * 64 + i * 16 + quad * 4 + r;
                float val = (acc[i][j][r] + ((z == 2) ? bias[m] : bias[n])) * scale;
                if (z < 2) {   // head-split [B,H,S,64]
                    const int b = m >> 11, s = m & 2047, h = n >> 6, d = n & 63;
                    out[(((size_t)(b * 16 + h) * 2048 + s) << 6) + d] = f2bf(val);
                } else {       // transposed [B,H,64,S]
                    const int h = m >> 6, d = m & 63, b = n >> 11, s = n & 2047;
                    out[((size_t)(b * 16 + h) * 64 + d) * 2048 + s] = f2bf(val);
                }
            }
        }
    }
}

// ---------------------------------------------------------------------------
// Output projection (R5-proven structure): out = ctx@Wo^T + bo, fp32 store.
// Both operands bf16. gl_lds staging, LDS double-buffer, counted vmcnt(4)
// (next tile's 4 loads stay in flight across barriers+MFMA), raw s_barrier.
// Chunked XCD swizzle: XCD k owns orig blocks [64k,64k+64) = 8 A-panels x
// all 8 n-blocks -> A(2MB)+W(2MB) L2-resident.
// ---------------------------------------------------------------------------
__global__ __launch_bounds__(256) void gemm_o(
    const unsigned short* __restrict__ A,
    const unsigned short* __restrict__ W,
    const float* __restrict__ bias,
    float* __restrict__ out)
{
    constexpr int K = 1024;
    __shared__ unsigned short Ash[2 * 128 * 32];   // [buf][row][k]
    __shared__ unsigned short Bsh[2 * 128 * 32];

    const int t    = threadIdx.x;
    const int w    = t >> 6;
    const int lane = t & 63;
    const int wm   = w >> 1, wn = w & 1;
    const int lr   = lane & 15, quad = lane >> 4;

    const int bid  = blockIdx.y * 8 + blockIdx.x;   // hw flat id, x fastest
    const int orig = (bid & 7) * 64 + (bid >> 3);   // chunked XCD swizzle
    const int n0 = (orig & 7) * 128;
    const int m0 = (orig >> 3) * 128;

    const int srow = t >> 2;
    const int skp  = (t & 3) * 8;

    const unsigned short* Ap0 = A + (size_t)(m0 + srow) * K + skp;
    const unsigned short* Ap1 = Ap0 + (size_t)64 * K;
    const unsigned short* Wp0 = W + (size_t)(n0 + srow) * K + skp;
    const unsigned short* Wp1 = Wp0 + (size_t)64 * K;
    unsigned short* lA0 = &Ash[w * 512];           // wave-uniform bases (buf 0)
    unsigned short* lA1 = &Ash[2048 + w * 512];
    unsigned short* lB0 = &Bsh[w * 512];
    unsigned short* lB1 = &Bsh[2048 + w * 512];

#define STAGE(buf, k0) do {                       \
        gl_lds16(Ap0 + (k0), lA0 + (buf) * 4096); \
        gl_lds16(Ap1 + (k0), lA1 + (buf) * 4096); \
        gl_lds16(Wp0 + (k0), lB0 + (buf) * 4096); \
        gl_lds16(Wp1 + (k0), lB1 + (buf) * 4096); \
    } while (0)

    f32x4 acc[4][4] = {};

    STAGE(0, 0);                         // prologue: tile 0 in flight
    int cur = 0;

    for (int k0 = 0; k0 < K; k0 += 32) {
        if (k0 + 32 < K) {
            STAGE(cur ^ 1, k0 + 32);     // prefetch next tile (stays in flight)
            asm volatile("s_waitcnt vmcnt(4)" ::: "memory");   // current tile done
        } else {
            asm volatile("s_waitcnt vmcnt(0)" ::: "memory");   // last tile: drain
        }
        __builtin_amdgcn_s_barrier();    // current tile visible to all waves
        __builtin_amdgcn_sched_barrier(0);

        bf16x8 af[4], bw[4];
#pragma unroll
        for (int i = 0; i < 4; i++)
            af[i] = *(const bf16x8*)&Ash[cur * 4096 + (wm * 64 + i * 16 + lr) * 32 + quad * 8];
#pragma unroll
        for (int j = 0; j < 4; j++)
            bw[j] = *(const bf16x8*)&Bsh[cur * 4096 + (wn * 64 + j * 16 + lr) * 32 + quad * 8];

#pragma unroll
        for (int i = 0; i < 4; i++)
#pragma unroll
            for (int j = 0; j < 4; j++)
                acc[i][j] = MFMA16(af[i], bw[j], acc[i][j]);

        __builtin_amdgcn_sched_barrier(0);
        __builtin_amdgcn_s_barrier();    // all waves done reading buf cur
        cur ^= 1;
    }
#undef STAGE

#pragma unroll
    for (int i = 0; i < 4; i++) {
#pragma unroll
        for (int j = 0; j < 4; j++) {
            const int n = n0 + wn * 64 + j * 16 + lr;
#pragma unroll
            for (int r = 0; r < 4; r++) {
                const int m = m0 + wm * 64 + i * 16 + quad * 4 + r;
                out[(size_t)m * 1024 + n] = acc[i][j][r] + bias[n];
            }
        }
    }
}

// ---------------------------------------------------------------------------
// Flash attention (sum-only softmax). Qh,Kh [B,H,S,64]; Vt [B,H,64,S] bf16.
// ctx out [B,S,1024] bf16. Grid (16,64), 4 waves, 32 q/wave, BK=64.
// LDS rows stride KS=72 shorts (144 B: b128-aligned, conflict-free patterns).
//
// Swapped QK^T (T12): lane (quad,lr) holds S[k=16*nt+4*quad+r][q=lr]; P stays
// in registers, PV A-frags rebuilt via cvt_pk + permlane32/16_swap (no Psh).
// Qh comes pre-scaled by 0.125*log2e -> p = exp2(s) directly (v_exp_f32).
//
// 32 q/wave: two 16-row Q tiles per wave share each K/V fragment read from
// LDS (read once, 2 MFMAs) -> LDS read bytes per unit work halved.
//
// T14 async-stage: regs for tile kb+64 loaded right after kb's ds_write;
// consumed at next iteration's ds_write -> compute phase hides HBM latency.
// ---------------------------------------------------------------------------
__global__ __launch_bounds__(256) void attn_kernel(
    const unsigned short* __restrict__ Qh,
    const unsigned short* __restrict__ Kh,
    const unsigned short* __restrict__ Vt,
    unsigned short* __restrict__ ctx)
{
    constexpr int KS = 72;
    __shared__ unsigned short Ksh[64 * KS];     // [k][d]
    __shared__ unsigned short Vts[64 * KS];     // [d][k]

    const int t    = threadIdx.x;
    const int w    = t >> 6;
    const int lane = t & 63;
    const int lr   = lane & 15, quad = lane >> 4;

    const int bh = blockIdx.y, qblk = blockIdx.x;
    const size_t base = (size_t)bh * 2048 * 64;
    const unsigned short* Qp = Qh + base;
    const unsigned short* Kg = Kh + base + (size_t)lane * 64 + w * 16;
    const unsigned short* Vg = Vt + base + (size_t)lane * 2048 + w * 16;

    const int q0 = qblk * 128 + w * 32;
    const unsigned short* qr0 = Qp + (size_t)(q0 + lr) * 64;
    const unsigned short* qr1 = Qp + (size_t)(q0 + 16 + lr) * 64;
    bf16x8 aq0 = *(const bf16x8*)(qr0 + quad * 8);
    bf16x8 aq1 = *(const bf16x8*)(qr0 + 32 + quad * 8);
    bf16x8 aq2 = *(const bf16x8*)(qr1 + quad * 8);
    bf16x8 aq3 = *(const bf16x8*)(qr1 + 32 + quad * 8);

    f32x4 Of0[4] = {}, Of1[4] = {};
    float ls0 = 0.f, ls1 = 0.f;

    // prologue: prefetch tile kb=0
    s16x8 kv0 = *(const s16x8*)(Kg);
    s16x8 kv1 = *(const s16x8*)(Kg + 8);
    s16x8 vv0 = *(const s16x8*)(Vg);
    s16x8 vv1 = *(const s16x8*)(Vg + 8);

    for (int kb = 0; kb < 2048; kb += 64) {
        __syncthreads();   // prior iteration's LDS reads complete
        *(s16x8*)&Ksh[lane * KS + w * 16]     = kv0;
        *(s16x8*)&Ksh[lane * KS + w * 16 + 8] = kv1;
        *(s16x8*)&Vts[lane * KS + w * 16]     = vv0;
        *(s16x8*)&Vts[lane * KS + w * 16 + 8] = vv1;

        // issue next tile's loads now; consumed at NEXT iteration's ds_write
        const int kn = (kb + 64) & 2047;     // wraps to 0 on last iter (unused)
        kv0 = *(const s16x8*)(Kg + (size_t)kn * 64);
        kv1 = *(const s16x8*)(Kg + (size_t)kn * 64 + 8);
        vv0 = *(const s16x8*)(Vg + kn);
        vv1 = *(const s16x8*)(Vg + kn + 8);

        __syncthreads();   // staged tile visible

        // ---- swapped QK^T: each K fragment read once, used by both q-tiles
        f32x4 pe0[4], pe1[4];
#pragma unroll
        for (int nt = 0; nt < 4; nt++) {
            const unsigned short* kr = &Ksh[(16 * nt + lr) * KS + quad * 8];
            bf16x8 k0 = *(const bf16x8*)kr;
            bf16x8 k1 = *(const bf16x8*)(kr + 32);
            f32x4 c0 = {}, c1 = {};
            c0 = MFMA16(k0, aq0, c0); c0 = MFMA16(k1, aq1, c0);
            c1 = MFMA16(k0, aq2, c1); c1 = MFMA16(k1, aq3, c1);
            f32x4 p0, p1;
#pragma unroll
            for (int r = 0; r < 4; r++) p0[r] = exp2_fast(c0[r]);
#pragma unroll
            for (int r = 0; r < 4; r++) p1[r] = exp2_fast(c1[r]);
            ls0 += (p0[0] + p0[1]) + (p0[2] + p0[3]);
            ls1 += (p1[0] + p1[1]) + (p1[2] + p1[3]);
            pe0[nt] = p0; pe1[nt] = p1;
        }

        // ---- PV A-fragments in-register (no LDS round-trip)
        bf16x8 pf00, pf01, pf10, pf11;
        pack_pf(pe0, pf00, pf01);
        pack_pf(pe1, pf10, pf11);

        // ---- PV : each V fragment read once, used by both q-tiles
#pragma unroll
        for (int dt = 0; dt < 4; dt++) {
            const unsigned short* vr = &Vts[(dt * 16 + lr) * KS + quad * 8];
            bf16x8 v0 = *(const bf16x8*)vr;
            bf16x8 v1 = *(const bf16x8*)(vr + 32);
            Of0[dt] = MFMA16(pf00, v0, Of0[dt]);
            Of0[dt] = MFMA16(pf01, v1, Of0[dt]);
            Of1[dt] = MFMA16(pf10, v0, Of1[dt]);
            Of1[dt] = MFMA16(pf11, v1, Of1[dt]);
        }
    }

    // lane's ls covers k={16nt+4quad+r} for q=lr; sum across quads -> all k
    ls0 += __shfl_xor(ls0, 16);
    ls0 += __shfl_xor(ls0, 32);
    ls1 += __shfl_xor(ls1, 16);
    ls1 += __shfl_xor(ls1, 32);

    const int b = bh >> 4, h = bh & 15;
#pragma unroll
    for (int r = 0; r < 4; r++) {
        const float inv0 = 1.0f / __shfl(ls0, quad * 4 + r, 64);
        const int qa = q0 + quad * 4 + r;
        unsigned short* cp0 = ctx + ((size_t)b * 2048 + qa) * 1024 + h * 64;
#pragma unroll
        for (int dt = 0; dt < 4; dt++)
            cp0[dt * 16 + lr] = f2bf(Of0[dt][r] * inv0);

        const float inv1 = 1.0f / __shfl(ls1, quad * 4 + r, 64);
        const int qb = q0 + 16 + quad * 4 + r;
        unsigned short* cp1 = ctx + ((size_t)b * 2048 + qb) * 1024 + h * 64;
#pragma unroll
        for (int dt = 0; dt < 4; dt++)
            cp1[dt * 16 + lr] = f2bf(Of1[dt][r] * inv1);
    }
}

// ---------------------------------------------------------------------------
extern "C" void kernel_launch(void* const* d_in, const int* in_sizes, int n_in,
                              void* d_out, int out_size, void* d_ws, size_t ws_size,
                              hipStream_t stream) {
    const float* Q  = (const float*)d_in[0];
    const float* K  = (const float*)d_in[1];
    const float* V  = (const float*)d_in[2];
    const float* Wq = (const float*)d_in[3];
    const float* bq = (const float*)d_in[4];
    const float* Wk = (const float*)d_in[5];
    const float* bk = (const float*)d_in[6];
    const float* Wv = (const float*)d_in[7];
    const float* bv = (const float*)d_in[8];
    const float* Wo = (const float*)d_in[9];
    const float* bo = (const float*)d_in[10];

    // workspace (bf16): Qh,Kh,Vtw,Ctx (16 MB each) + Wob (2 MB)
    const size_t EB = (size_t)8192 * 1024;
    const size_t EW = (size_t)1024 * 1024;
    unsigned short* Qh  = (unsigned short*)d_ws;
    unsigned short* Kh  = Qh  + EB;
    unsigned short* Vtw = Kh  + EB;
    unsigned short* Ctx = Vtw + EB;
    unsigned short* Wob = Ctx + EB;

    // 1/sqrt(64) * log2(e): scores*log2e folded into Qh so attn uses exp2
    const float QSCALE = 0.125f * 1.44269504088896340736f;

    dim3 tb(256);
    cvt_kernel<<<(int)(EW / 8 / 256), tb, 0, stream>>>(Wo, Wob, (int)(EW / 8));
    proj_kernel<<<dim3(8, 64, 3), tb, 0, stream>>>(
        Q, K, V, Wq, Wk, Wv, bq, bk, bv, Qh, Kh, Vtw, QSCALE);
    attn_kernel<<<dim3(16, 64), tb, 0, stream>>>(Qh, Kh, Vtw, Ctx);
    gemm_o<<<dim3(8, 64), tb, 0, stream>>>(Ctx, Wob, bo, (float*)d_out);
}

// Round 9
// 349.332 us; speedup vs baseline: 1.1182x; 1.1182x over previous
//
#include <hip/hip_runtime.h>
#include <hip/hip_bf16.h>

// ---------------------------------------------------------------------------
// MHA forward: fp32 I/O, bf16 MFMA compute. B=4,S=2048,D=1024,H=16,DK=64.
// 4 dispatches:
//   0. cvt4: Q,K,V,Wq,Wk,Wv,Wo -> bf16 in ONE launch (~147 MB stream)
//   1. proj_kernel grid(8,64,3): z=0 Qh=(Q@Wq^T+bq)*qscale, z=1 Kh, z=2
//      Vt=(V@Wv^T+bv)^T. All-bf16 gl_lds staging + LDS double-buffer +
//      counted vmcnt(4) (R5-proven loop; reg-staged fp32+cvt was 2-3x slower
//      in every A/B: R6 gemm_o 122 vs 55, R7/R8 proj 53/GEMM).
//   2. attn_kernel: flash attention (sum-only softmax; swapped QK^T,
//      in-register P, T14 async-stage, 32 q-rows/wave).
//   3. gemm_o: out = ctx@Wo^T+bo (same gl_lds structure).
// ---------------------------------------------------------------------------

typedef float  f32x4  __attribute__((ext_vector_type(4)));
typedef __bf16 bf16x8 __attribute__((ext_vector_type(8)));
typedef short  s16x8  __attribute__((ext_vector_type(8)));
typedef int    i32x4  __attribute__((ext_vector_type(4)));

#define MFMA16(a,b,c) __builtin_amdgcn_mfma_f32_16x16x32_bf16((a),(b),(c),0,0,0)

__device__ __forceinline__ unsigned short f2bf(float f) {
    union { float f; unsigned u; } v; v.f = f;
    unsigned r = v.u + 0x7fffu + ((v.u >> 16) & 1u);   // RNE
    return (unsigned short)(r >> 16);
}

__device__ __forceinline__ s16x8 cvt8(const float* __restrict__ p) {
    f32x4 x = *(const f32x4*)p;
    f32x4 y = *(const f32x4*)(p + 4);
    s16x8 r;
    r[0] = (short)f2bf(x[0]); r[1] = (short)f2bf(x[1]);
    r[2] = (short)f2bf(x[2]); r[3] = (short)f2bf(x[3]);
    r[4] = (short)f2bf(y[0]); r[5] = (short)f2bf(y[1]);
    r[6] = (short)f2bf(y[2]); r[7] = (short)f2bf(y[3]);
    return r;
}

// async global->LDS, 16 B per lane; LDS dest = wave-uniform base + lane*16
__device__ __forceinline__ void gl_lds16(const void* g, void* l) {
    __builtin_amdgcn_global_load_lds(
        (const __attribute__((address_space(1))) unsigned int*)g,
        (__attribute__((address_space(3))) unsigned int*)l, 16, 0, 0);
}

// raw v_exp_f32: D = 2^S0
__device__ __forceinline__ float exp2_fast(float x) {
    float r;
    asm("v_exp_f32 %0, %1" : "=v"(r) : "v"(x));
    return r;
}

// pack 2 f32 -> 1 dword of 2 bf16 (RNE). D[15:0]=bf16(lo), D[31:16]=bf16(hi)
__device__ __forceinline__ int cvtpk_bf16(float lo, float hi) {
    int r;
    asm("v_cvt_pk_bf16_f32 %0, %1, %2" : "=v"(r) : "v"(lo), "v"(hi));
    return r;
}
// a.row1(32 lanes) <-> b.row0: a'=[a.lo32,b.lo32], b'=[a.hi32,b.hi32]
__device__ __forceinline__ void plswap32(int& a, int& b) {
    asm("v_permlane32_swap_b32 %0, %1" : "+v"(a), "+v"(b));
}
// odd 16-rows of a <-> even 16-rows of b
__device__ __forceinline__ void plswap16(int& a, int& b) {
    asm("v_permlane16_swap_b32 %0, %1" : "+v"(a), "+v"(b));
}

// P-row (lane-local, S^T layout) -> two PV A-fragment dwords x2
__device__ __forceinline__ void pack_pf(const f32x4 pe[4], bf16x8& pf0, bf16x8& pf1) {
    int a0 = cvtpk_bf16(pe[0][0], pe[0][1]);
    int a1 = cvtpk_bf16(pe[0][2], pe[0][3]);
    int b0 = cvtpk_bf16(pe[1][0], pe[1][1]);
    int b1 = cvtpk_bf16(pe[1][2], pe[1][3]);
    plswap32(a0, b0); plswap32(a1, b1);
    plswap16(a0, b0); plswap16(a1, b1);
    i32x4 f0; f0[0] = a0; f0[1] = a1; f0[2] = b0; f0[3] = b1;
    int c0 = cvtpk_bf16(pe[2][0], pe[2][1]);
    int c1 = cvtpk_bf16(pe[2][2], pe[2][3]);
    int d0 = cvtpk_bf16(pe[3][0], pe[3][1]);
    int d1 = cvtpk_bf16(pe[3][2], pe[3][3]);
    plswap32(c0, d0); plswap32(c1, d1);
    plswap16(c0, d0); plswap16(c1, d1);
    i32x4 f1; f1[0] = c0; f1[1] = c1; f1[2] = d0; f1[3] = d1;
    pf0 = __builtin_bit_cast(bf16x8, f0);
    pf1 = __builtin_bit_cast(bf16x8, f1);
}

// ---------------------------------------------------------------------------
// All seven fp32->bf16 conversions in one launch.
// Q,K,V: 4096 blocks each (8M elems). Wq,Wk,Wv,Wo: 512 blocks each (1M).
// ---------------------------------------------------------------------------
__global__ __launch_bounds__(256) void cvt4_kernel(
    const float* __restrict__ Q,  const float* __restrict__ K,
    const float* __restrict__ V,
    const float* __restrict__ Wq, const float* __restrict__ Wk,
    const float* __restrict__ Wv, const float* __restrict__ Wo,
    unsigned short* __restrict__ Qb, unsigned short* __restrict__ Kb,
    unsigned short* __restrict__ Vb,
    unsigned short* __restrict__ Wqb, unsigned short* __restrict__ Wkb,
    unsigned short* __restrict__ Wvb, unsigned short* __restrict__ Wob)
{
    const int bid = blockIdx.x;
    const float* s;
    unsigned short* d;
    int idx;
    if (bid < 4096)       { s = Q; d = Qb; idx = bid; }
    else if (bid < 8192)  { s = K; d = Kb; idx = bid - 4096; }
    else if (bid < 12288) { s = V; d = Vb; idx = bid - 8192; }
    else {
        const int wb = bid - 12288, ws = wb >> 9;
        idx = wb & 511;
        s = (ws == 0) ? Wq : (ws == 1) ? Wk : (ws == 2) ? Wv : Wo;
        d = (ws == 0) ? Wqb : (ws == 1) ? Wkb : (ws == 2) ? Wvb : Wob;
    }
    const size_t i = (size_t)idx * 256 + threadIdx.x;
    *(s16x8*)(d + i * 8) = cvt8(s + i * 8);
}

// ---------------------------------------------------------------------------
// Fused QKV projection, all-bf16, gl_lds structure. Grid (8,64,3), 128x128
// tile, BK=32, LDS double-buffer, counted vmcnt(4), raw s_barrier.
// z=0: Qh[b,h,s,d] = (Q@Wq^T+bq)*qscale  (bf16, head-split)
// z=1: Kh likewise, scale 1
// z=2: Vt[b,h,d,s] = (V@Wv^T+bv)^T       (A-side=Wv, W-side=V)
// XCD decode: blockIdx.x (=XCD id) owns one 1024-row operand chunk (2MB) +
// the full 2MB counter-operand -> L2-resident.
// ---------------------------------------------------------------------------
__global__ __launch_bounds__(256) void proj_kernel(
    const unsigned short* __restrict__ Qb, const unsigned short* __restrict__ Kb,
    const unsigned short* __restrict__ Vb,
    const unsigned short* __restrict__ Wqb, const unsigned short* __restrict__ Wkb,
    const unsigned short* __restrict__ Wvb,
    const float* __restrict__ bqf, const float* __restrict__ bkf,
    const float* __restrict__ bvf,
    unsigned short* __restrict__ Qh, unsigned short* __restrict__ Kh,
    unsigned short* __restrict__ Vtw, float qscale)
{
    constexpr int K = 1024;
    __shared__ unsigned short Ash[2 * 128 * 32];   // [buf][row][k]
    __shared__ unsigned short Bsh[2 * 128 * 32];

    const int t    = threadIdx.x;
    const int w    = t >> 6;
    const int lane = t & 63;
    const int wm   = w >> 1, wn = w & 1;
    const int lr   = lane & 15, quad = lane >> 4;

    const int z = blockIdx.z;
    const unsigned short *A, *W;
    const float* bias;
    float scale;
    unsigned short* out;
    if (z == 0)      { A = Qb;  W = Wqb; bias = bqf; out = Qh;  scale = qscale; }
    else if (z == 1) { A = Kb;  W = Wkb; bias = bkf; out = Kh;  scale = 1.0f; }
    else             { A = Wvb; W = Vb;  bias = bvf; out = Vtw; scale = 1.0f; }

    int m0, n0;
    if (z < 2) {   // m: 64 tiles (seq), n: 8 tiles (weight). XCD x owns m-chunk.
        m0 = (blockIdx.x * 8 + (blockIdx.y >> 3)) * 128;
        n0 = (blockIdx.y & 7) * 128;
    } else {       // m: 8 tiles (Wv rows), n: 64 tiles (V rows). XCD x owns V-chunk.
        m0 = (blockIdx.y & 7) * 128;
        n0 = (blockIdx.x * 8 + (blockIdx.y >> 3)) * 128;
    }

    // staging chunk c = t: LDS offset c*16 B -> row = t>>2, kchunk=(t&3)*8
    const int srow = t >> 2;
    const int skp  = (t & 3) * 8;

    const unsigned short* Ap0 = A + (size_t)(m0 + srow) * K + skp;
    const unsigned short* Ap1 = Ap0 + (size_t)64 * K;
    const unsigned short* Wp0 = W + (size_t)(n0 + srow) * K + skp;
    const unsigned short* Wp1 = Wp0 + (size_t)64 * K;
    unsigned short* lA0 = &Ash[w * 512];           // wave-uniform bases (buf 0)
    unsigned short* lA1 = &Ash[2048 + w * 512];
    unsigned short* lB0 = &Bsh[w * 512];
    unsigned short* lB1 = &Bsh[2048 + w * 512];

#define STAGE(buf, k0) do {                       \
        gl_lds16(Ap0 + (k0), lA0 + (buf) * 4096); \
        gl_lds16(Ap1 + (k0), lA1 + (buf) * 4096); \
        gl_lds16(Wp0 + (k0), lB0 + (buf) * 4096); \
        gl_lds16(Wp1 + (k0), lB1 + (buf) * 4096); \
    } while (0)

    f32x4 acc[4][4] = {};

    STAGE(0, 0);                         // prologue: tile 0 in flight
    int cur = 0;

    for (int k0 = 0; k0 < K; k0 += 32) {
        if (k0 + 32 < K) {
            STAGE(cur ^ 1, k0 + 32);     // prefetch next tile (stays in flight)
            asm volatile("s_waitcnt vmcnt(4)" ::: "memory");   // current tile done
        } else {
            asm volatile("s_waitcnt vmcnt(0)" ::: "memory");   // last tile: drain
        }
        __builtin_amdgcn_s_barrier();    // current tile visible to all waves
        __builtin_amdgcn_sched_barrier(0);

        bf16x8 af[4], bw[4];
#pragma unroll
        for (int i = 0; i < 4; i++)
            af[i] = *(const bf16x8*)&Ash[cur * 4096 + (wm * 64 + i * 16 + lr) * 32 + quad * 8];
#pragma unroll
        for (int j = 0; j < 4; j++)
            bw[j] = *(const bf16x8*)&Bsh[cur * 4096 + (wn * 64 + j * 16 + lr) * 32 + quad * 8];

#pragma unroll
        for (int i = 0; i < 4; i++)
#pragma unroll
            for (int j = 0; j < 4; j++)
                acc[i][j] = MFMA16(af[i], bw[j], acc[i][j]);

        __builtin_amdgcn_sched_barrier(0);
        __builtin_amdgcn_s_barrier();    // all waves done reading buf cur
        cur ^= 1;
    }
#undef STAGE

    // epilogue: C/D row = quad*4+r (m-side), col = lr (n-side)
#pragma unroll
    for (int i = 0; i < 4; i++) {
#pragma unroll
        for (int j = 0; j < 4; j++) {
            const int n = n0 + wn * 64 + j * 16 + lr;
#pragma unroll
            for (int r = 0; r < 4; r++) {
                const int m = m0 + wm * 64 + i * 16 + quad * 4 + r;
                float val = (acc[i][j][r] + ((z == 2) ? bias[m] : bias[n])) * scale;
                if (z < 2) {   // head-split [B,H,S,64]
                    const int b = m >> 11, s = m & 2047, h = n >> 6, d = n & 63;
                    out[(((size_t)(b * 16 + h) * 2048 + s) << 6) + d] = f2bf(val);
                } else {       // transposed [B,H,64,S]
                    const int h = m >> 6, d = m & 63, b = n >> 11, s = n & 2047;
                    out[((size_t)(b * 16 + h) * 64 + d) * 2048 + s] = f2bf(val);
                }
            }
        }
    }
}

// ---------------------------------------------------------------------------
// Output projection (R5-proven structure): out = ctx@Wo^T + bo, fp32 store.
// Both operands bf16. gl_lds staging, LDS double-buffer, counted vmcnt(4),
// raw s_barrier. Chunked XCD swizzle: XCD k owns 8 A-panels x all 8 n-blocks.
// ---------------------------------------------------------------------------
__global__ __launch_bounds__(256) void gemm_o(
    const unsigned short* __restrict__ A,
    const unsigned short* __restrict__ W,
    const float* __restrict__ bias,
    float* __restrict__ out)
{
    constexpr int K = 1024;
    __shared__ unsigned short Ash[2 * 128 * 32];   // [buf][row][k]
    __shared__ unsigned short Bsh[2 * 128 * 32];

    const int t    = threadIdx.x;
    const int w    = t >> 6;
    const int lane = t & 63;
    const int wm   = w >> 1, wn = w & 1;
    const int lr   = lane & 15, quad = lane >> 4;

    const int bid  = blockIdx.y * 8 + blockIdx.x;   // hw flat id, x fastest
    const int orig = (bid & 7) * 64 + (bid >> 3);   // chunked XCD swizzle
    const int n0 = (orig & 7) * 128;
    const int m0 = (orig >> 3) * 128;

    const int srow = t >> 2;
    const int skp  = (t & 3) * 8;

    const unsigned short* Ap0 = A + (size_t)(m0 + srow) * K + skp;
    const unsigned short* Ap1 = Ap0 + (size_t)64 * K;
    const unsigned short* Wp0 = W + (size_t)(n0 + srow) * K + skp;
    const unsigned short* Wp1 = Wp0 + (size_t)64 * K;
    unsigned short* lA0 = &Ash[w * 512];           // wave-uniform bases (buf 0)
    unsigned short* lA1 = &Ash[2048 + w * 512];
    unsigned short* lB0 = &Bsh[w * 512];
    unsigned short* lB1 = &Bsh[2048 + w * 512];

#define STAGE(buf, k0) do {                       \
        gl_lds16(Ap0 + (k0), lA0 + (buf) * 4096); \
        gl_lds16(Ap1 + (k0), lA1 + (buf) * 4096); \
        gl_lds16(Wp0 + (k0), lB0 + (buf) * 4096); \
        gl_lds16(Wp1 + (k0), lB1 + (buf) * 4096); \
    } while (0)

    f32x4 acc[4][4] = {};

    STAGE(0, 0);                         // prologue: tile 0 in flight
    int cur = 0;

    for (int k0 = 0; k0 < K; k0 += 32) {
        if (k0 + 32 < K) {
            STAGE(cur ^ 1, k0 + 32);     // prefetch next tile (stays in flight)
            asm volatile("s_waitcnt vmcnt(4)" ::: "memory");   // current tile done
        } else {
            asm volatile("s_waitcnt vmcnt(0)" ::: "memory");   // last tile: drain
        }
        __builtin_amdgcn_s_barrier();    // current tile visible to all waves
        __builtin_amdgcn_sched_barrier(0);

        bf16x8 af[4], bw[4];
#pragma unroll
        for (int i = 0; i < 4; i++)
            af[i] = *(const bf16x8*)&Ash[cur * 4096 + (wm * 64 + i * 16 + lr) * 32 + quad * 8];
#pragma unroll
        for (int j = 0; j < 4; j++)
            bw[j] = *(const bf16x8*)&Bsh[cur * 4096 + (wn * 64 + j * 16 + lr) * 32 + quad * 8];

#pragma unroll
        for (int i = 0; i < 4; i++)
#pragma unroll
            for (int j = 0; j < 4; j++)
                acc[i][j] = MFMA16(af[i], bw[j], acc[i][j]);

        __builtin_amdgcn_sched_barrier(0);
        __builtin_amdgcn_s_barrier();    // all waves done reading buf cur
        cur ^= 1;
    }
#undef STAGE

#pragma unroll
    for (int i = 0; i < 4; i++) {
#pragma unroll
        for (int j = 0; j < 4; j++) {
            const int n = n0 + wn * 64 + j * 16 + lr;
#pragma unroll
            for (int r = 0; r < 4; r++) {
                const int m = m0 + wm * 64 + i * 16 + quad * 4 + r;
                out[(size_t)m * 1024 + n] = acc[i][j][r] + bias[n];
            }
        }
    }
}

// ---------------------------------------------------------------------------
// Flash attention (sum-only softmax). Qh,Kh [B,H,S,64]; Vt [B,H,64,S] bf16.
// ctx out [B,S,1024] bf16. Grid (16,64), 4 waves, 32 q/wave, BK=64.
// LDS rows stride KS=72 shorts (144 B: b128-aligned, conflict-free patterns).
//
// Swapped QK^T (T12): lane (quad,lr) holds S[k=16*nt+4*quad+r][q=lr]; P stays
// in registers, PV A-frags rebuilt via cvt_pk + permlane32/16_swap (no Psh).
// Qh comes pre-scaled by 0.125*log2e -> p = exp2(s) directly (v_exp_f32).
//
// 32 q/wave: two 16-row Q tiles per wave share each K/V fragment read from
// LDS (read once, 2 MFMAs) -> LDS read bytes per unit work halved.
//
// T14 async-stage: regs for tile kb+64 loaded right after kb's ds_write;
// consumed at next iteration's ds_write -> compute phase hides HBM latency.
// ---------------------------------------------------------------------------
__global__ __launch_bounds__(256) void attn_kernel(
    const unsigned short* __restrict__ Qh,
    const unsigned short* __restrict__ Kh,
    const unsigned short* __restrict__ Vt,
    unsigned short* __restrict__ ctx)
{
    constexpr int KS = 72;
    __shared__ unsigned short Ksh[64 * KS];     // [k][d]
    __shared__ unsigned short Vts[64 * KS];     // [d][k]

    const int t    = threadIdx.x;
    const int w    = t >> 6;
    const int lane = t & 63;
    const int lr   = lane & 15, quad = lane >> 4;

    const int bh = blockIdx.y, qblk = blockIdx.x;
    const size_t base = (size_t)bh * 2048 * 64;
    const unsigned short* Qp = Qh + base;
    const unsigned short* Kg = Kh + base + (size_t)lane * 64 + w * 16;
    const unsigned short* Vg = Vt + base + (size_t)lane * 2048 + w * 16;

    const int q0 = qblk * 128 + w * 32;
    const unsigned short* qr0 = Qp + (size_t)(q0 + lr) * 64;
    const unsigned short* qr1 = Qp + (size_t)(q0 + 16 + lr) * 64;
    bf16x8 aq0 = *(const bf16x8*)(qr0 + quad * 8);
    bf16x8 aq1 = *(const bf16x8*)(qr0 + 32 + quad * 8);
    bf16x8 aq2 = *(const bf16x8*)(qr1 + quad * 8);
    bf16x8 aq3 = *(const bf16x8*)(qr1 + 32 + quad * 8);

    f32x4 Of0[4] = {}, Of1[4] = {};
    float ls0 = 0.f, ls1 = 0.f;

    // prologue: prefetch tile kb=0
    s16x8 kv0 = *(const s16x8*)(Kg);
    s16x8 kv1 = *(const s16x8*)(Kg + 8);
    s16x8 vv0 = *(const s16x8*)(Vg);
    s16x8 vv1 = *(const s16x8*)(Vg + 8);

    for (int kb = 0; kb < 2048; kb += 64) {
        __syncthreads();   // prior iteration's LDS reads complete
        *(s16x8*)&Ksh[lane * KS + w * 16]     = kv0;
        *(s16x8*)&Ksh[lane * KS + w * 16 + 8] = kv1;
        *(s16x8*)&Vts[lane * KS + w * 16]     = vv0;
        *(s16x8*)&Vts[lane * KS + w * 16 + 8] = vv1;

        // issue next tile's loads now; consumed at NEXT iteration's ds_write
        const int kn = (kb + 64) & 2047;     // wraps to 0 on last iter (unused)
        kv0 = *(const s16x8*)(Kg + (size_t)kn * 64);
        kv1 = *(const s16x8*)(Kg + (size_t)kn * 64 + 8);
        vv0 = *(const s16x8*)(Vg + kn);
        vv1 = *(const s16x8*)(Vg + kn + 8);

        __syncthreads();   // staged tile visible

        // ---- swapped QK^T: each K fragment read once, used by both q-tiles
        f32x4 pe0[4], pe1[4];
#pragma unroll
        for (int nt = 0; nt < 4; nt++) {
            const unsigned short* kr = &Ksh[(16 * nt + lr) * KS + quad * 8];
            bf16x8 k0 = *(const bf16x8*)kr;
            bf16x8 k1 = *(const bf16x8*)(kr + 32);
            f32x4 c0 = {}, c1 = {};
            c0 = MFMA16(k0, aq0, c0); c0 = MFMA16(k1, aq1, c0);
            c1 = MFMA16(k0, aq2, c1); c1 = MFMA16(k1, aq3, c1);
            f32x4 p0, p1;
#pragma unroll
            for (int r = 0; r < 4; r++) p0[r] = exp2_fast(c0[r]);
#pragma unroll
            for (int r = 0; r < 4; r++) p1[r] = exp2_fast(c1[r]);
            ls0 += (p0[0] + p0[1]) + (p0[2] + p0[3]);
            ls1 += (p1[0] + p1[1]) + (p1[2] + p1[3]);
            pe0[nt] = p0; pe1[nt] = p1;
        }

        // ---- PV A-fragments in-register (no LDS round-trip)
        bf16x8 pf00, pf01, pf10, pf11;
        pack_pf(pe0, pf00, pf01);
        pack_pf(pe1, pf10, pf11);

        // ---- PV : each V fragment read once, used by both q-tiles
#pragma unroll
        for (int dt = 0; dt < 4; dt++) {
            const unsigned short* vr = &Vts[(dt * 16 + lr) * KS + quad * 8];
            bf16x8 v0 = *(const bf16x8*)vr;
            bf16x8 v1 = *(const bf16x8*)(vr + 32);
            Of0[dt] = MFMA16(pf00, v0, Of0[dt]);
            Of0[dt] = MFMA16(pf01, v1, Of0[dt]);
            Of1[dt] = MFMA16(pf10, v0, Of1[dt]);
            Of1[dt] = MFMA16(pf11, v1, Of1[dt]);
        }
    }

    // lane's ls covers k={16nt+4quad+r} for q=lr; sum across quads -> all k
    ls0 += __shfl_xor(ls0, 16);
    ls0 += __shfl_xor(ls0, 32);
    ls1 += __shfl_xor(ls1, 16);
    ls1 += __shfl_xor(ls1, 32);

    const int b = bh >> 4, h = bh & 15;
#pragma unroll
    for (int r = 0; r < 4; r++) {
        const float inv0 = 1.0f / __shfl(ls0, quad * 4 + r, 64);
        const int qa = q0 + quad * 4 + r;
        unsigned short* cp0 = ctx + ((size_t)b * 2048 + qa) * 1024 + h * 64;
#pragma unroll
        for (int dt = 0; dt < 4; dt++)
            cp0[dt * 16 + lr] = f2bf(Of0[dt][r] * inv0);

        const float inv1 = 1.0f / __shfl(ls1, quad * 4 + r, 64);
        const int qb = q0 + 16 + quad * 4 + r;
        unsigned short* cp1 = ctx + ((size_t)b * 2048 + qb) * 1024 + h * 64;
#pragma unroll
        for (int dt = 0; dt < 4; dt++)
            cp1[dt * 16 + lr] = f2bf(Of1[dt][r] * inv1);
    }
}

// ---------------------------------------------------------------------------
extern "C" void kernel_launch(void* const* d_in, const int* in_sizes, int n_in,
                              void* d_out, int out_size, void* d_ws, size_t ws_size,
                              hipStream_t stream) {
    const float* Q  = (const float*)d_in[0];
    const float* K  = (const float*)d_in[1];
    const float* V  = (const float*)d_in[2];
    const float* Wq = (const float*)d_in[3];
    const float* bq = (const float*)d_in[4];
    const float* Wk = (const float*)d_in[5];
    const float* bk = (const float*)d_in[6];
    const float* Wv = (const float*)d_in[7];
    const float* bv = (const float*)d_in[8];
    const float* Wo = (const float*)d_in[9];
    const float* bo = (const float*)d_in[10];

    // workspace (bf16 elems): Qb,Kb,Vb (8M ea) + 4 weights (1M ea) +
    // Qh,Kh,Vtw (8M ea) = 52M shorts = 104 MB. Ctx aliases Qb (dead after proj).
    const size_t EB = (size_t)8192 * 1024;
    const size_t EW = (size_t)1024 * 1024;
    unsigned short* Qb  = (unsigned short*)d_ws;
    unsigned short* Kb  = Qb  + EB;
    unsigned short* Vb  = Kb  + EB;
    unsigned short* Wqb = Vb  + EB;
    unsigned short* Wkb = Wqb + EW;
    unsigned short* Wvb = Wkb + EW;
    unsigned short* Wob = Wvb + EW;
    unsigned short* Qh  = Wob + EW;
    unsigned short* Kh  = Qh  + EB;
    unsigned short* Vtw = Kh  + EB;
    unsigned short* Ctx = Qb;                 // Qb dead after proj

    // 1/sqrt(64) * log2(e): scores*log2e folded into Qh so attn uses exp2
    const float QSCALE = 0.125f * 1.44269504088896340736f;

    dim3 tb(256);
    cvt4_kernel<<<14336, tb, 0, stream>>>(Q, K, V, Wq, Wk, Wv, Wo,
                                          Qb, Kb, Vb, Wqb, Wkb, Wvb, Wob);
    proj_kernel<<<dim3(8, 64, 3), tb, 0, stream>>>(
        Qb, Kb, Vb, Wqb, Wkb, Wvb, bq, bk, bv, Qh, Kh, Vtw, QSCALE);
    attn_kernel<<<dim3(16, 64), tb, 0, stream>>>(Qh, Kh, Vtw, Ctx);
    gemm_o<<<dim3(8, 64), tb, 0, stream>>>(Ctx, Wob, bo, (float*)d_out);
}